// Round 1
// baseline (398.562 us; speedup 1.0000x reference)
//
#include <hip/hip_runtime.h>

// MetaUpSampler: dynamic per-subpixel 3x3 conv.
// Shapes (fixed by setup_inputs): N=4, C=64, H=W=192, s=4, outC=3.
//   lr_features (4,64,192,192) f32 | W1 (3,256) | b1 (256) | W2 (256,1728) | b2 (1728) | sr_scale=4
// out: (4,3,768,768) f32
//
// Stage A: lw[kc][po] = sum_h relu(pos[p]@W1+b1)[h] * W2[h][kc*3+o] + b2[kc*3+o]
//   kc = c*9 + (di*3+dj)  (im2col channel-major, kernel-pos-minor, matches torch unfold)
//   po = p*3 + o, p = si*4+sj
// Stage B: out[n][o][4h+si][4w+sj] = sum_kc cols[n,h*W+w,kc] * lw[kc][p*3+o]

#define NB   4
#define CCH  64
#define HH   192
#define WWD  192
#define SS   4
#define S2   16
#define OC   3
#define PO   48       // S2*OC
#define KC   576      // CCH*9
#define HID  256
#define W2LD 1728     // KC*OC

__global__ void lw_kernel(const float* __restrict__ W1, const float* __restrict__ b1,
                          const float* __restrict__ W2, const float* __restrict__ b2,
                          float* __restrict__ lw) {
    __shared__ float hlds[S2 * 257];   // +1 pad: bank spread for p-indexed reads
    const int tid = threadIdx.x;       // tid == hidden index h in [0,256)
    const float w0 = W1[tid], w1 = W1[HID + tid], w2 = W1[2 * HID + tid], bb = b1[tid];
#pragma unroll
    for (int p = 0; p < S2; ++p) {
        const float pi = (float)(p / SS) * 0.25f;
        const float pj = (float)(p % SS) * 0.25f;
        const float hv = 0.25f * w0 + pi * w1 + pj * w2 + bb;
        hlds[p * 257 + tid] = hv > 0.f ? hv : 0.f;
    }
    __syncthreads();
    const int e  = blockIdx.x * 256 + tid;   // e in [0, 27648) == kc*48 + po
    const int kc = e / PO;
    const int po = e % PO;
    const int p  = po / OC;
    const int o  = po % OC;
    const int col = kc * OC + o;
    float sum = b2[col];
    const float* __restrict__ hrow = &hlds[p * 257];
#pragma unroll 8
    for (int h = 0; h < HID; ++h)
        sum += hrow[h] * W2[h * W2LD + col];
    lw[e] = sum;   // layout: [c][tap][po], contiguous chunks of 8 channels = 3456 floats
}

__global__ __launch_bounds__(128) void meta_up_kernel(const float* __restrict__ x,
                                                      const float* __restrict__ lw,
                                                      float* __restrict__ out) {
    __shared__ float wlds[8 * 9 * PO];   // 3456 floats = 13.8 KB, one 8-channel chunk
    const int tid  = threadIdx.x;
    const int flat = blockIdx.x * 128 + tid;       // 1152*128 == 4*192*192 exactly
    const int n    = flat / (HH * WWD);
    const int rem  = flat % (HH * WWD);
    const int h    = rem / WWD;
    const int w    = rem % WWD;

    float acc[PO];
#pragma unroll
    for (int i = 0; i < PO; ++i) acc[i] = 0.f;

    for (int cc = 0; cc < 8; ++cc) {
        __syncthreads();                            // protect previous chunk readers
        for (int idx = tid; idx < 8 * 9 * PO; idx += 128)
            wlds[idx] = lw[cc * (8 * 9 * PO) + idx];
        __syncthreads();

#pragma unroll 1
        for (int c8 = 0; c8 < 8; ++c8) {
            const int c = cc * 8 + c8;
            const float* __restrict__ xb = x + ((size_t)(n * CCH + c) * HH) * WWD;
            float patch[9];
#pragma unroll
            for (int di = 0; di < 3; ++di) {
                const int hs = h + di - 1;
#pragma unroll
                for (int dj = 0; dj < 3; ++dj) {
                    const int ws_ = w + dj - 1;
                    const bool ok = ((unsigned)hs < (unsigned)HH) && ((unsigned)ws_ < (unsigned)WWD);
                    patch[di * 3 + dj] = ok ? xb[hs * WWD + ws_] : 0.f;
                }
            }
#pragma unroll
            for (int t = 0; t < 9; ++t) {
                const float pv = patch[t];
                const float4* __restrict__ w4 = (const float4*)&wlds[(c8 * 9 + t) * PO];
#pragma unroll
                for (int g = 0; g < 12; ++g) {
                    const float4 wv = w4[g];
                    acc[g * 4 + 0] += pv * wv.x;
                    acc[g * 4 + 1] += pv * wv.y;
                    acc[g * 4 + 2] += pv * wv.z;
                    acc[g * 4 + 3] += pv * wv.w;
                }
            }
        }
    }

    // Epilogue: po = (si*4+sj)*3 + o -> out[n][o][4h+si][4w+sj]; float4 over sj.
#pragma unroll
    for (int o = 0; o < OC; ++o) {
#pragma unroll
        for (int si = 0; si < SS; ++si) {
            const float4 v = make_float4(acc[(si * SS + 0) * OC + o],
                                         acc[(si * SS + 1) * OC + o],
                                         acc[(si * SS + 2) * OC + o],
                                         acc[(si * SS + 3) * OC + o]);
            const size_t off = (((size_t)n * OC + o) * (SS * HH) + (size_t)(h * SS + si)) * (SS * WWD)
                             + (size_t)w * SS;
            *(float4*)&out[off] = v;
        }
    }
}

extern "C" void kernel_launch(void* const* d_in, const int* in_sizes, int n_in,
                              void* d_out, int out_size, void* d_ws, size_t ws_size,
                              hipStream_t stream) {
    const float* x  = (const float*)d_in[0];
    const float* W1 = (const float*)d_in[1];
    const float* b1 = (const float*)d_in[2];
    const float* W2 = (const float*)d_in[3];
    const float* b2 = (const float*)d_in[4];
    // d_in[5] = sr_scale (int, ==4): shapes hardcoded to the setup.
    float* out = (float*)d_out;
    float* lw  = (float*)d_ws;          // 27648 floats = 110 KB scratch

    lw_kernel<<<KC * PO / 256, 256, 0, stream>>>(W1, b1, W2, b2, lw);
    meta_up_kernel<<<(NB * HH * WWD) / 128, 128, 0, stream>>>(x, lw, out);
}

// Round 2
// 391.875 us; speedup vs baseline: 1.0171x; 1.0171x over previous
//
#include <hip/hip_runtime.h>

// MetaUpSampler via bf16 MFMA.
// GEMM view: out2d[m][po] = sum_{tap,c} x[n,c,h+di-1,w+dj-1] * lw[tap][c][po]
//   m = n*H*W + h*W + w (147456), po = (si*4+sj)*3 + o (48), K = 9 taps x 64 ch.
// Stage A: tiny MLP -> lwb (bf16) in layout [tap][po][c]  (tap=di*3+dj)
// Stage B: per block: 64 pixels x 48 outputs; x tile staged in LDS transposed
//   (channel-innermost, XOR-swizzled); 9 taps x 2 K-chunks of 16x16x32 MFMA.

#define HH   192
#define WWD  192
#define SS   4
#define OC   3
#define PO   48
#define HID  256
#define W2LD 1728

typedef short  bf16x8 __attribute__((ext_vector_type(8)));
typedef float  f32x4  __attribute__((ext_vector_type(4)));

static __device__ __forceinline__ short f2bf(float f) {
    unsigned u = __float_as_uint(f);
    unsigned r = (u + 0x7fffu + ((u >> 16) & 1u)) >> 16;   // RNE
    return (short)r;
}

// ---------------- Stage A: MLP -> dynamic weights, bf16, [tap][po][c] -------
__global__ __launch_bounds__(256) void lw_kernel(
        const float* __restrict__ W1, const float* __restrict__ b1,
        const float* __restrict__ W2, const float* __restrict__ b2,
        short* __restrict__ lwb) {
    __shared__ float hlds[16 * HID];   // [p][h]
    const int tid = threadIdx.x;       // == hidden index h
    const float w0 = W1[tid], w1 = W1[HID + tid], w2 = W1[2 * HID + tid], bb = b1[tid];
#pragma unroll
    for (int p = 0; p < 16; ++p) {
        const float pi = (float)(p >> 2) * 0.25f;
        const float pj = (float)(p & 3) * 0.25f;
        const float hv = 0.25f * w0 + pi * w1 + pj * w2 + bb;
        hlds[p * HID + tid] = hv > 0.f ? hv : 0.f;
    }
    __syncthreads();
    const int col = blockIdx.x * 256 + tid;       // output column of W2 (0..1727)
    if (col >= W2LD) return;
    const int pg = blockIdx.y * 4;                // 4 p-values per block row
    float a0 = 0.f, a1 = 0.f, a2 = 0.f, a3 = 0.f;
    const float* __restrict__ h0 = &hlds[(pg + 0) * HID];
    const float* __restrict__ h1 = &hlds[(pg + 1) * HID];
    const float* __restrict__ h2 = &hlds[(pg + 2) * HID];
    const float* __restrict__ h3 = &hlds[(pg + 3) * HID];
#pragma unroll 4
    for (int h = 0; h < HID; ++h) {
        const float v = W2[h * W2LD + col];       // coalesced across threads
        a0 += h0[h] * v; a1 += h1[h] * v; a2 += h2[h] * v; a3 += h3[h] * v;
    }
    const float bv = b2[col];
    // col = kc*3 + o, kc = c*9 + tap  ->  dest (tap, po = p*3+o, c)
    const int o = col % 3, kc = col / 3;
    const int tap = kc % 9, c = kc / 9;
    const int base = (tap * PO) * 64 + c;
    lwb[base + ((pg + 0) * 3 + o) * 64] = f2bf(a0 + bv);
    lwb[base + ((pg + 1) * 3 + o) * 64] = f2bf(a1 + bv);
    lwb[base + ((pg + 2) * 3 + o) * 64] = f2bf(a2 + bv);
    lwb[base + ((pg + 3) * 3 + o) * 64] = f2bf(a3 + bv);
}

// ---------------- Stage B: MFMA dynamic conv --------------------------------
// Block: 64 pixels (one row segment) x all 48 po. 4 waves x 16 pixels.
// xlds[r][j][c]: r=0..2 rows h-1..h+1, j=0..65 cols w0-1..w0+64, c=0..63,
// c innermost, 16B blocks XOR-swizzled by (j&7) to avoid 128B-stride conflicts.
__global__ __launch_bounds__(256, 4) void meta_up_mfma(
        const float* __restrict__ x, const short* __restrict__ lwb,
        float* __restrict__ out) {
    __shared__ short xlds[3 * 66 * 64];   // 25,344 B
    const int tid = threadIdx.x;
    const int bid = blockIdx.x;
    const int wch = bid % 3;
    const int h   = (bid / 3) % HH;
    const int n   = bid / (3 * HH);
    const int w0  = wch * 64;

    if (tid < 192) {
        const int c = tid & 63, r = tid >> 6;
        const int gr = h + r - 1;
        const bool rok = (unsigned)gr < (unsigned)HH;
        const float* __restrict__ xp =
            x + (((size_t)(n * 64 + c)) * HH + gr) * WWD + (w0 - 1);
        const int cb = c >> 3, cl = c & 7;
#pragma unroll 2
        for (int j = 0; j < 66; ++j) {
            const int gc = w0 - 1 + j;
            const float v = (rok && (unsigned)gc < (unsigned)WWD) ? xp[j] : 0.f;
            xlds[(r * 66 + j) * 64 + ((cb ^ (j & 7)) << 3) + cl] = f2bf(v);
        }
    }
    __syncthreads();

    const int lane = tid & 63, wv = tid >> 6;
    const int quad = lane >> 4, l15 = lane & 15;
    f32x4 accs[3];
#pragma unroll
    for (int t = 0; t < 3; ++t) accs[t] = (f32x4){0.f, 0.f, 0.f, 0.f};

    const int colbase = wv * 16 + l15;
#pragma unroll 3
    for (int tap = 0; tap < 9; ++tap) {
        const int di = tap / 3, dj = tap % 3;
        const int col = colbase + dj;                       // 0..65
        const short* __restrict__ arow = &xlds[(di * 66 + col) * 64];
        const int cswz = col & 7;
        const short* __restrict__ bbase = lwb + (tap * PO + l15) * 64 + quad * 8;
#pragma unroll
        for (int kc2 = 0; kc2 < 2; ++kc2) {
            const int kb8 = kc2 * 4 + quad;                 // 16B-block index of k
            bf16x8 a  = *(const bf16x8*)&arow[(kb8 ^ cswz) << 3];
            bf16x8 b0 = *(const bf16x8*)&bbase[kc2 * 32];
            bf16x8 b1 = *(const bf16x8*)&bbase[1024 + kc2 * 32];   // +16 po
            bf16x8 b2 = *(const bf16x8*)&bbase[2048 + kc2 * 32];   // +32 po
            accs[0] = __builtin_amdgcn_mfma_f32_16x16x32_bf16(a, b0, accs[0], 0, 0, 0);
            accs[1] = __builtin_amdgcn_mfma_f32_16x16x32_bf16(a, b1, accs[1], 0, 0, 0);
            accs[2] = __builtin_amdgcn_mfma_f32_16x16x32_bf16(a, b2, accs[2], 0, 0, 0);
        }
    }

    // D layout: col(po') = lane&15, row(m) = quad*4 + reg.
    const int wbase = w0 + wv * 16 + quad * 4;
#pragma unroll
    for (int t = 0; t < 3; ++t) {
        const int po = t * 16 + l15;
        const int o  = po % 3;
        const int p  = po / 3;
        const int si = p >> 2, sj = p & 3;
        const size_t rowbase =
            ((size_t)(n * OC + o) * (SS * HH) + (size_t)(SS * h + si)) * (SS * WWD) + sj;
#pragma unroll
        for (int r = 0; r < 4; ++r)
            out[rowbase + (size_t)(wbase + r) * SS] = accs[t][r];
    }
}

extern "C" void kernel_launch(void* const* d_in, const int* in_sizes, int n_in,
                              void* d_out, int out_size, void* d_ws, size_t ws_size,
                              hipStream_t stream) {
    const float* x  = (const float*)d_in[0];
    const float* W1 = (const float*)d_in[1];
    const float* b1 = (const float*)d_in[2];
    const float* W2 = (const float*)d_in[3];
    const float* b2 = (const float*)d_in[4];
    float* out = (float*)d_out;
    short* lwb = (short*)d_ws;   // 27648 bf16 = 55 KB

    lw_kernel<<<dim3(7, 4), 256, 0, stream>>>(W1, b1, W2, b2, lwb);
    meta_up_mfma<<<4 * HH * 3, 256, 0, stream>>>(x, lwb, out);
}

// Round 3
// 201.315 us; speedup vs baseline: 1.9798x; 1.9466x over previous
//
#include <hip/hip_runtime.h>

// MetaUpSampler via bf16 MFMA — round 3.
// GEMM view: out2d[m][po] = sum_{tap,c} x[n,c,h+di-1,w+dj-1] * lwb[tap][c][po]
//   m = pixel (147456), po = (si*4+sj)*3+o (48), K = 9 taps x 64 ch.
// Stage A (unchanged): MLP -> lwb bf16 [tap][po][c].
// Stage B: 1x64 pixel strip per block, 3 waves (one po-tile each).
//   - x staged COALESCED (lane = w-col) + transposed to [r][j][c] via
//     ds_write_b128, 16B-block XOR swizzle (cb ^ (j&7)).
//   - B fragments held in registers (18 x bf16x8 = 72 VGPR), loaded once.
//   - XCD-swizzled block id: each XCD owns a contiguous (n,h) band so h+-1
//     halo rows hit that XCD's L2.

#define HH   192
#define WWD  192
#define SS   4
#define OC   3
#define PO   48
#define HID  256
#define W2LD 1728

typedef short  bf16x8 __attribute__((ext_vector_type(8)));
typedef float  f32x4  __attribute__((ext_vector_type(4)));

static __device__ __forceinline__ short f2bf(float f) {
    unsigned u = __float_as_uint(f);
    unsigned r = (u + 0x7fffu + ((u >> 16) & 1u)) >> 16;   // RNE
    return (short)r;
}

// ---------------- Stage A: MLP -> dynamic weights, bf16, [tap][po][c] -------
__global__ __launch_bounds__(256) void lw_kernel(
        const float* __restrict__ W1, const float* __restrict__ b1,
        const float* __restrict__ W2, const float* __restrict__ b2,
        short* __restrict__ lwb) {
    __shared__ float hlds[16 * HID];   // [p][h]
    const int tid = threadIdx.x;       // == hidden index h
    const float w0 = W1[tid], w1 = W1[HID + tid], w2 = W1[2 * HID + tid], bb = b1[tid];
#pragma unroll
    for (int p = 0; p < 16; ++p) {
        const float pi = (float)(p >> 2) * 0.25f;
        const float pj = (float)(p & 3) * 0.25f;
        const float hv = 0.25f * w0 + pi * w1 + pj * w2 + bb;
        hlds[p * HID + tid] = hv > 0.f ? hv : 0.f;
    }
    __syncthreads();
    const int col = blockIdx.x * 256 + tid;       // W2 column (0..1727)
    if (col >= W2LD) return;
    const int pg = blockIdx.y * 4;                // 4 p-values per block row
    float a0 = 0.f, a1 = 0.f, a2 = 0.f, a3 = 0.f;
    const float* __restrict__ h0 = &hlds[(pg + 0) * HID];
    const float* __restrict__ h1 = &hlds[(pg + 1) * HID];
    const float* __restrict__ h2 = &hlds[(pg + 2) * HID];
    const float* __restrict__ h3 = &hlds[(pg + 3) * HID];
#pragma unroll 4
    for (int h = 0; h < HID; ++h) {
        const float v = W2[h * W2LD + col];       // coalesced
        a0 += h0[h] * v; a1 += h1[h] * v; a2 += h2[h] * v; a3 += h3[h] * v;
    }
    const float bv = b2[col];
    const int o = col % 3, kc = col / 3;
    const int tap = kc % 9, c = kc / 9;
    const int base = (tap * PO) * 64 + c;
    lwb[base + ((pg + 0) * 3 + o) * 64] = f2bf(a0 + bv);
    lwb[base + ((pg + 1) * 3 + o) * 64] = f2bf(a1 + bv);
    lwb[base + ((pg + 2) * 3 + o) * 64] = f2bf(a2 + bv);
    lwb[base + ((pg + 3) * 3 + o) * 64] = f2bf(a3 + bv);
}

// ---------------- Stage B: MFMA dynamic conv --------------------------------
__global__ __launch_bounds__(192, 3) void meta_up_mfma(
        const float* __restrict__ x, const short* __restrict__ lwb,
        float* __restrict__ out) {
    __shared__ short xlds[3 * 66 * 64];   // 25,344 B; [r][j][c], c in XOR'd 16B blocks

    // XCD-band swizzle: 2304 strips = 8 XCDs x 288; contiguous (n,h) per XCD.
    const int strip = (blockIdx.x & 7) * 288 + (blockIdx.x >> 3);
    const int n   = strip / (HH * 3);
    const int rem = strip % (HH * 3);
    const int h   = rem / 3;
    const int wch = rem % 3;
    const int w0  = wch * 64;

    const int tid  = threadIdx.x;
    const int lane = tid & 63, wv = tid >> 6;     // wv = staging row AND po-tile
    const int quad = lane >> 4, l15 = lane & 15;

    // B fragments: one po-tile (16 po) per wave, all 9 taps x 2 K-chunks.
    bf16x8 Bfrag[18];
#pragma unroll
    for (int tap = 0; tap < 9; ++tap)
#pragma unroll
        for (int kc2 = 0; kc2 < 2; ++kc2)
            Bfrag[tap * 2 + kc2] = *(const bf16x8*)
                &lwb[(tap * PO + wv * 16 + l15) * 64 + kc2 * 32 + quad * 8];

    // Stage x: wave wv handles row gr = h+wv-1. Lane = column j (coalesced
    // 256B wave-reads per channel); gather 8 channels -> one ds_write_b128.
    {
        const int gr  = h + wv - 1;
        const bool rok = (unsigned)gr < (unsigned)HH;
        const int gc  = w0 - 1 + lane;
        const bool cok = rok && ((unsigned)gc < (unsigned)WWD);
        const float* __restrict__ xr =
            x + ((size_t)n * 64 * HH + (size_t)(rok ? gr : 0)) * WWD + (cok ? gc : 0);
#pragma unroll
        for (int cb = 0; cb < 8; ++cb) {
            bf16x8 pk;
#pragma unroll
            for (int cc = 0; cc < 8; ++cc) {
                const float vv = cok ? xr[(size_t)(cb * 8 + cc) * HH * WWD] : 0.f;
                pk[cc] = f2bf(vv);
            }
            *(bf16x8*)&xlds[(wv * 66 + lane) * 64 + ((cb ^ (lane & 7)) << 3)] = pk;
        }
        if (lane < 16) {                 // tail columns j = 64, 65
            const int jt = 64 + (lane >> 3);
            const int cb = lane & 7;
            const int gc2 = w0 - 1 + jt;
            const bool cok2 = rok && ((unsigned)gc2 < (unsigned)WWD);
            bf16x8 pk;
#pragma unroll
            for (int cc = 0; cc < 8; ++cc) {
                const float vv = cok2 ?
                    x[((size_t)(n * 64 + cb * 8 + cc) * HH + gr) * WWD + gc2] : 0.f;
                pk[cc] = f2bf(vv);
            }
            *(bf16x8*)&xlds[(wv * 66 + jt) * 64 + ((cb ^ (jt & 7)) << 3)] = pk;
        }
    }
    __syncthreads();

    // Main loop: 4 m-tiles x 18 (tap,kc2) -> 72 MFMAs per wave.
    f32x4 acc[4];
#pragma unroll
    for (int mt = 0; mt < 4; ++mt) acc[mt] = (f32x4){0.f, 0.f, 0.f, 0.f};

#pragma unroll 3
    for (int tap = 0; tap < 9; ++tap) {
        const int di = tap / 3, dj = tap % 3;
#pragma unroll
        for (int kc2 = 0; kc2 < 2; ++kc2) {
            const bf16x8 b = Bfrag[tap * 2 + kc2];
#pragma unroll
            for (int mt = 0; mt < 4; ++mt) {
                const int col = mt * 16 + l15 + dj;           // 0..65
                const int blk = (kc2 * 4 + quad) ^ (col & 7);
                bf16x8 a = *(const bf16x8*)&xlds[(di * 66 + col) * 64 + (blk << 3)];
                acc[mt] = __builtin_amdgcn_mfma_f32_16x16x32_bf16(a, b, acc[mt], 0, 0, 0);
            }
        }
    }

    // Epilogue: D col = lane&15 = po', row = quad*4+reg = pixel in m-tile.
    const int po = wv * 16 + l15;
    const int o  = po % 3;
    const int p  = po / 3;
    const int si = p >> 2, sj = p & 3;
    const size_t rowbase =
        ((size_t)(n * OC + o) * (SS * HH) + (size_t)(SS * h + si)) * (SS * WWD) + sj;
#pragma unroll
    for (int mt = 0; mt < 4; ++mt) {
        const int wpix = w0 + mt * 16 + quad * 4;
#pragma unroll
        for (int r4 = 0; r4 < 4; ++r4)
            out[rowbase + (size_t)(wpix + r4) * SS] = acc[mt][r4];
    }
}

extern "C" void kernel_launch(void* const* d_in, const int* in_sizes, int n_in,
                              void* d_out, int out_size, void* d_ws, size_t ws_size,
                              hipStream_t stream) {
    const float* x  = (const float*)d_in[0];
    const float* W1 = (const float*)d_in[1];
    const float* b1 = (const float*)d_in[2];
    const float* W2 = (const float*)d_in[3];
    const float* b2 = (const float*)d_in[4];
    float* out = (float*)d_out;
    short* lwb = (short*)d_ws;   // 27648 bf16 = 55 KB

    lw_kernel<<<dim3(7, 4), 256, 0, stream>>>(W1, b1, W2, b2, lwb);
    meta_up_mfma<<<4 * HH * 3, 192, 0, stream>>>(x, lwb, out);
}

// Round 4
// 192.213 us; speedup vs baseline: 2.0735x; 1.0474x over previous
//
#include <hip/hip_runtime.h>

// MetaUpSampler via bf16 MFMA — round 4.
// GEMM view: out2d[m][po] = sum_{tap,c} x[n,c,h+di-1,w+dj-1] * lwb[tap][c][po]
// Stage A: MLP -> lwb bf16 [tap][po][c]; hidden transposed [h][p] in LDS,
//   float4 W2 loads, 16 accums/thread (4 cols x 4 p) — latency-tolerant.
// Stage B: 1x64 strip per block, 3 waves (one po-tile each);
//   coalesced+transposed x staging (XOR-swizzled [r][j][c]);
//   B-fragments in registers; NEW: epilogue transposes D through LDS so
//   global stores are full-line float4 (fixes 5.4x write amplification).

#define HH   192
#define WWD  192
#define SS   4
#define OC   3
#define PO   48
#define HID  256
#define W2LD 1728

typedef short  bf16x8 __attribute__((ext_vector_type(8)));
typedef float  f32x4  __attribute__((ext_vector_type(4)));

static __device__ __forceinline__ short f2bf(float f) {
    unsigned u = __float_as_uint(f);
    unsigned r = (u + 0x7fffu + ((u >> 16) & 1u)) >> 16;   // RNE
    return (short)r;
}

// ---------------- Stage A: MLP -> dynamic weights, bf16, [tap][po][c] -------
// Grid: 7 blocks x 256 threads. Thread = (col-group of 4, p-group of 4).
__global__ __launch_bounds__(256) void lw_kernel(
        const float* __restrict__ W1, const float* __restrict__ b1,
        const float* __restrict__ W2, const float* __restrict__ b2,
        short* __restrict__ lwb) {
    __shared__ float hlds[HID * 16];   // [h][p] transposed, 16 KB
    const int tid = threadIdx.x;       // == hidden index h for the MLP part
    {
        const float w0 = W1[tid], w1 = W1[HID + tid], w2 = W1[2 * HID + tid], bb = b1[tid];
#pragma unroll
        for (int g = 0; g < 4; ++g) {
            float4 hv;
            float* hp = (float*)&hv;
#pragma unroll
            for (int pp = 0; pp < 4; ++pp) {
                const int p = g * 4 + pp;
                const float pi = (float)(p >> 2) * 0.25f;
                const float pj = (float)(p & 3) * 0.25f;
                const float v = 0.25f * w0 + pi * w1 + pj * w2 + bb;
                hp[pp] = v > 0.f ? v : 0.f;
            }
            *(float4*)&hlds[tid * 16 + g * 4] = hv;
        }
    }
    __syncthreads();

    const int pg = tid >> 6;                       // wave-uniform p-group
    const int cg = blockIdx.x * 64 + (tid & 63);   // col-group (4 cols each)
    if (cg >= W2LD / 4) return;                    // 432 groups
    const int col0 = cg * 4;

    float a[4][4];                                  // [pp][cc]
#pragma unroll
    for (int pp = 0; pp < 4; ++pp)
#pragma unroll
        for (int cc = 0; cc < 4; ++cc) a[pp][cc] = 0.f;

#pragma unroll 8
    for (int h = 0; h < HID; ++h) {
        const float4 wv = *(const float4*)&W2[h * W2LD + col0];     // coalesced 16B
        const float4 hv = *(const float4*)&hlds[h * 16 + pg * 4];   // uniform b128
        const float* wp = (const float*)&wv;
        const float* hp = (const float*)&hv;
#pragma unroll
        for (int pp = 0; pp < 4; ++pp)
#pragma unroll
            for (int cc = 0; cc < 4; ++cc)
                a[pp][cc] += hp[pp] * wp[cc];
    }

#pragma unroll
    for (int cc = 0; cc < 4; ++cc) {
        const int col = col0 + cc;
        const float bv = b2[col];
        const int o = col % 3, kc = col / 3;
        const int tap = kc % 9, c = kc / 9;
#pragma unroll
        for (int pp = 0; pp < 4; ++pp) {
            const int p = pg * 4 + pp;
            lwb[(tap * PO + p * 3 + o) * 64 + c] = f2bf(a[pp][cc] + bv);
        }
    }
}

// ---------------- Stage B: MFMA dynamic conv --------------------------------
__global__ __launch_bounds__(192, 3) void meta_up_mfma(
        const float* __restrict__ x, const short* __restrict__ lwb,
        float* __restrict__ out) {
    __shared__ __align__(16) short smem[3 * 66 * 64];   // 25,344 B
    short* xlds = smem;                    // [r][j][c], c in XOR'd 16B blocks
    float* obuf = (float*)smem;            // reused post-MFMA: 12 x 260 floats

    // XCD-band swizzle: 2304 strips = 8 XCDs x 288; contiguous (n,h) per XCD.
    const int strip = (blockIdx.x & 7) * 288 + (blockIdx.x >> 3);
    const int n   = strip / (HH * 3);
    const int rem = strip % (HH * 3);
    const int h   = rem / 3;
    const int wch = rem % 3;
    const int w0  = wch * 64;

    const int tid  = threadIdx.x;
    const int lane = tid & 63, wv = tid >> 6;     // wv = staging row AND po-tile
    const int quad = lane >> 4, l15 = lane & 15;

    // B fragments: one po-tile (16 po) per wave, all 9 taps x 2 K-chunks.
    bf16x8 Bfrag[18];
#pragma unroll
    for (int tap = 0; tap < 9; ++tap)
#pragma unroll
        for (int kc2 = 0; kc2 < 2; ++kc2)
            Bfrag[tap * 2 + kc2] = *(const bf16x8*)
                &lwb[(tap * PO + wv * 16 + l15) * 64 + kc2 * 32 + quad * 8];

    // Stage x: wave wv handles row gr = h+wv-1. Lane = column j (coalesced);
    // gather 8 channels -> one ds_write_b128.
    {
        const int gr  = h + wv - 1;
        const bool rok = (unsigned)gr < (unsigned)HH;
        const int gc  = w0 - 1 + lane;
        const bool cok = rok && ((unsigned)gc < (unsigned)WWD);
        const float* __restrict__ xr =
            x + ((size_t)n * 64 * HH + (size_t)(rok ? gr : 0)) * WWD + (cok ? gc : 0);
#pragma unroll
        for (int cb = 0; cb < 8; ++cb) {
            bf16x8 pk;
#pragma unroll
            for (int cc = 0; cc < 8; ++cc) {
                const float vv = cok ? xr[(size_t)(cb * 8 + cc) * HH * WWD] : 0.f;
                pk[cc] = f2bf(vv);
            }
            *(bf16x8*)&xlds[(wv * 66 + lane) * 64 + ((cb ^ (lane & 7)) << 3)] = pk;
        }
        if (lane < 16) {                 // tail columns j = 64, 65
            const int jt = 64 + (lane >> 3);
            const int cb = lane & 7;
            const int gc2 = w0 - 1 + jt;
            const bool cok2 = rok && ((unsigned)gc2 < (unsigned)WWD);
            bf16x8 pk;
#pragma unroll
            for (int cc = 0; cc < 8; ++cc) {
                const float vv = cok2 ?
                    x[((size_t)(n * 64 + cb * 8 + cc) * HH + gr) * WWD + gc2] : 0.f;
                pk[cc] = f2bf(vv);
            }
            *(bf16x8*)&xlds[(wv * 66 + jt) * 64 + ((cb ^ (jt & 7)) << 3)] = pk;
        }
    }
    __syncthreads();

    // Main loop: 4 m-tiles x 18 (tap,kc2) -> 72 MFMAs per wave.
    f32x4 acc[4];
#pragma unroll
    for (int mt = 0; mt < 4; ++mt) acc[mt] = (f32x4){0.f, 0.f, 0.f, 0.f};

#pragma unroll 3
    for (int tap = 0; tap < 9; ++tap) {
        const int di = tap / 3, dj = tap % 3;
#pragma unroll
        for (int kc2 = 0; kc2 < 2; ++kc2) {
            const bf16x8 b = Bfrag[tap * 2 + kc2];
#pragma unroll
            for (int mt = 0; mt < 4; ++mt) {
                const int col = mt * 16 + l15 + dj;           // 0..65
                const int blk = (kc2 * 4 + quad) ^ (col & 7);
                bf16x8 a = *(const bf16x8*)&xlds[(di * 66 + col) * 64 + (blk << 3)];
                acc[mt] = __builtin_amdgcn_mfma_f32_16x16x32_bf16(a, b, acc[mt], 0, 0, 0);
            }
        }
    }

    // Epilogue: transpose D through LDS -> full-line coalesced stores.
    // obuf row osi = o*4+si holds 256 floats: col = wl*4 + sj (wl = local pixel).
    __syncthreads();                       // all xlds reads complete
    {
        const int po = wv * 16 + l15;
        const int o  = po % 3;
        const int p  = po / 3;
        const int si = p >> 2, sj = p & 3;
        const int osi = o * 4 + si;
#pragma unroll
        for (int mt = 0; mt < 4; ++mt)
#pragma unroll
            for (int r4 = 0; r4 < 4; ++r4) {
                const int wl = mt * 16 + quad * 4 + r4;
                obuf[osi * 260 + wl * 4 + sj] = acc[mt][r4];
            }
    }
    __syncthreads();
    {
        const int osi = tid >> 4;          // 0..11
        const int c16 = tid & 15;
        const int o = osi >> 2, si = osi & 3;
        const size_t base =
            ((size_t)(n * OC + o) * (SS * HH) + (size_t)(SS * h + si)) * (SS * WWD)
            + (size_t)(4 * w0) + c16 * 16;
        const float* __restrict__ src = &obuf[osi * 260 + c16 * 16];
#pragma unroll
        for (int i = 0; i < 4; ++i)        // 64B contiguous per thread
            *(float4*)&out[base + i * 4] = *(const float4*)&src[i * 4];
    }
}

extern "C" void kernel_launch(void* const* d_in, const int* in_sizes, int n_in,
                              void* d_out, int out_size, void* d_ws, size_t ws_size,
                              hipStream_t stream) {
    const float* x  = (const float*)d_in[0];
    const float* W1 = (const float*)d_in[1];
    const float* b1 = (const float*)d_in[2];
    const float* W2 = (const float*)d_in[3];
    const float* b2 = (const float*)d_in[4];
    float* out = (float*)d_out;
    short* lwb = (short*)d_ws;   // 27648 bf16 = 55 KB

    lw_kernel<<<7, 256, 0, stream>>>(W1, b1, W2, b2, lwb);
    meta_up_mfma<<<4 * HH * 3, 192, 0, stream>>>(x, lwb, out);
}

// Round 5
// 131.400 us; speedup vs baseline: 3.0332x; 1.4628x over previous
//
#include <hip/hip_runtime.h>

// MetaUpSampler via bf16 MFMA — round 5.
// GEMM view: out2d[m][po] = sum_{tap,c} x[n,c,h+di-1,w+dj-1] * lwb[tap][c][po]
// Stage A: MLP -> lwb bf16 [tap][po][c]. 28 blocks, 1 W2 col/thread,
//   coalesced scalar loads unrolled x16, hidden [h][p] in LDS (uniform b128).
// Stage B: 1x64 strip per block, 3 waves (one po-tile each);
//   coalesced+transposed x staging (XOR-swizzled [r][j][c]);
//   B-fragments in VGPRs — tap loop FULLY unrolled (R4's partial unroll made
//   Bfrag[] runtime-indexed -> scratch spill -> 127 MB of phantom HBM traffic,
//   VGPR_Count=44 was the smoking gun);
//   epilogue transposes D through LDS -> full-line float4 stores.

#define HH   192
#define WWD  192
#define SS   4
#define OC   3
#define PO   48
#define HID  256
#define W2LD 1728

typedef short  bf16x8 __attribute__((ext_vector_type(8)));
typedef float  f32x4  __attribute__((ext_vector_type(4)));

static __device__ __forceinline__ short f2bf(float f) {
    unsigned u = __float_as_uint(f);
    unsigned r = (u + 0x7fffu + ((u >> 16) & 1u)) >> 16;   // RNE
    return (short)r;
}

// ---------------- Stage A: MLP -> dynamic weights, bf16, [tap][po][c] -------
// Grid: dim3(7,4) x 256 threads. Thread = one W2 column, 4 p-values (pg=blockIdx.y).
__global__ __launch_bounds__(256) void lw_kernel(
        const float* __restrict__ W1, const float* __restrict__ b1,
        const float* __restrict__ W2, const float* __restrict__ b2,
        short* __restrict__ lwb) {
    __shared__ float hlds[HID * 16];   // [h][p] transposed, 16 KB
    const int tid = threadIdx.x;       // == hidden index h for the MLP part
    {
        const float w0 = W1[tid], w1 = W1[HID + tid], w2 = W1[2 * HID + tid], bb = b1[tid];
#pragma unroll
        for (int g = 0; g < 4; ++g) {
            float4 hv;
            float* hp = (float*)&hv;
#pragma unroll
            for (int pp = 0; pp < 4; ++pp) {
                const int p = g * 4 + pp;
                const float pi = (float)(p >> 2) * 0.25f;
                const float pj = (float)(p & 3) * 0.25f;
                const float v = 0.25f * w0 + pi * w1 + pj * w2 + bb;
                hp[pp] = v > 0.f ? v : 0.f;
            }
            *(float4*)&hlds[tid * 16 + g * 4] = hv;
        }
    }
    __syncthreads();

    const int col = blockIdx.x * 256 + tid;   // 0..1791 (guard at 1728)
    const int pg  = blockIdx.y;               // p-group (wave-uniform)
    if (col < W2LD) {
        float a0 = 0.f, a1 = 0.f, a2 = 0.f, a3 = 0.f;
#pragma unroll 16
        for (int h = 0; h < HID; ++h) {
            const float v  = W2[h * W2LD + col];                    // coalesced 4B
            const float4 hv = *(const float4*)&hlds[h * 16 + pg * 4]; // uniform b128
            a0 += hv.x * v; a1 += hv.y * v; a2 += hv.z * v; a3 += hv.w * v;
        }
        const float bv = b2[col];
        const int o = col % 3, kc = col / 3;
        const int tap = kc % 9, c = kc / 9;
        const int p0 = pg * 4;
        lwb[(tap * PO + (p0 + 0) * 3 + o) * 64 + c] = f2bf(a0 + bv);
        lwb[(tap * PO + (p0 + 1) * 3 + o) * 64 + c] = f2bf(a1 + bv);
        lwb[(tap * PO + (p0 + 2) * 3 + o) * 64 + c] = f2bf(a2 + bv);
        lwb[(tap * PO + (p0 + 3) * 3 + o) * 64 + c] = f2bf(a3 + bv);
    }
}

// ---------------- Stage B: MFMA dynamic conv --------------------------------
__global__ __launch_bounds__(192, 3) void meta_up_mfma(
        const float* __restrict__ x, const short* __restrict__ lwb,
        float* __restrict__ out) {
    __shared__ __align__(16) short smem[3 * 66 * 64];   // 25,344 B
    short* xlds = smem;                    // [r][j][c], c in XOR'd 16B blocks
    float* obuf = (float*)smem;            // reused post-MFMA: 12 x 260 floats

    // XCD-band swizzle: 2304 strips = 8 XCDs x 288; contiguous (n,h) per XCD.
    const int strip = (blockIdx.x & 7) * 288 + (blockIdx.x >> 3);
    const int n   = strip / (HH * 3);
    const int rem = strip % (HH * 3);
    const int h   = rem / 3;
    const int wch = rem % 3;
    const int w0  = wch * 64;

    const int tid  = threadIdx.x;
    const int lane = tid & 63, wv = tid >> 6;     // wv = staging row AND po-tile
    const int quad = lane >> 4, l15 = lane & 15;

    // B fragments: one po-tile (16 po) per wave, all 9 taps x 2 K-chunks.
    // ALL indices compile-time constant -> stays in VGPRs.
    bf16x8 Bfrag[18];
#pragma unroll
    for (int tap = 0; tap < 9; ++tap)
#pragma unroll
        for (int kc2 = 0; kc2 < 2; ++kc2)
            Bfrag[tap * 2 + kc2] = *(const bf16x8*)
                &lwb[(tap * PO + wv * 16 + l15) * 64 + kc2 * 32 + quad * 8];

    // Stage x: wave wv handles row gr = h+wv-1. Lane = column j (coalesced);
    // gather 8 channels -> one ds_write_b128.
    {
        const int gr  = h + wv - 1;
        const bool rok = (unsigned)gr < (unsigned)HH;
        const int gc  = w0 - 1 + lane;
        const bool cok = rok && ((unsigned)gc < (unsigned)WWD);
        const float* __restrict__ xr =
            x + ((size_t)n * 64 * HH + (size_t)(rok ? gr : 0)) * WWD + (cok ? gc : 0);
#pragma unroll
        for (int cb = 0; cb < 8; ++cb) {
            bf16x8 pk;
#pragma unroll
            for (int cc = 0; cc < 8; ++cc) {
                const float vv = cok ? xr[(size_t)(cb * 8 + cc) * HH * WWD] : 0.f;
                pk[cc] = f2bf(vv);
            }
            *(bf16x8*)&xlds[(wv * 66 + lane) * 64 + ((cb ^ (lane & 7)) << 3)] = pk;
        }
        if (lane < 16) {                 // tail columns j = 64, 65
            const int jt = 64 + (lane >> 3);
            const int cb = lane & 7;
            const int gc2 = w0 - 1 + jt;
            const bool cok2 = rok && ((unsigned)gc2 < (unsigned)WWD);
            bf16x8 pk;
#pragma unroll
            for (int cc = 0; cc < 8; ++cc) {
                const float vv = cok2 ?
                    x[((size_t)(n * 64 + cb * 8 + cc) * HH + gr) * WWD + gc2] : 0.f;
                pk[cc] = f2bf(vv);
            }
            *(bf16x8*)&xlds[(wv * 66 + jt) * 64 + ((cb ^ (jt & 7)) << 3)] = pk;
        }
    }
    __syncthreads();

    // Main loop: FULLY unrolled 9 taps x 2 K-chunks x 4 m-tiles = 72 MFMAs.
    f32x4 acc[4];
#pragma unroll
    for (int mt = 0; mt < 4; ++mt) acc[mt] = (f32x4){0.f, 0.f, 0.f, 0.f};

#pragma unroll
    for (int tap = 0; tap < 9; ++tap) {
        const int di = tap / 3, dj = tap % 3;
#pragma unroll
        for (int kc2 = 0; kc2 < 2; ++kc2) {
            const bf16x8 b = Bfrag[tap * 2 + kc2];
#pragma unroll
            for (int mt = 0; mt < 4; ++mt) {
                const int col = mt * 16 + l15 + dj;           // 0..65
                const int blk = (kc2 * 4 + quad) ^ (col & 7);
                bf16x8 a = *(const bf16x8*)&xlds[(di * 66 + col) * 64 + (blk << 3)];
                acc[mt] = __builtin_amdgcn_mfma_f32_16x16x32_bf16(a, b, acc[mt], 0, 0, 0);
            }
        }
    }

    // Epilogue: transpose D through LDS -> full-line coalesced stores.
    __syncthreads();                       // all xlds reads complete
    {
        const int po = wv * 16 + l15;
        const int o  = po % 3;
        const int p  = po / 3;
        const int si = p >> 2, sj = p & 3;
        const int osi = o * 4 + si;
#pragma unroll
        for (int mt = 0; mt < 4; ++mt)
#pragma unroll
            for (int r4 = 0; r4 < 4; ++r4) {
                const int wl = mt * 16 + quad * 4 + r4;
                obuf[osi * 260 + wl * 4 + sj] = acc[mt][r4];
            }
    }
    __syncthreads();
    {
        const int osi = tid >> 4;          // 0..11
        const int c16 = tid & 15;
        const int o = osi >> 2, si = osi & 3;
        const size_t base =
            ((size_t)(n * OC + o) * (SS * HH) + (size_t)(SS * h + si)) * (SS * WWD)
            + (size_t)(4 * w0) + c16 * 16;
        const float* __restrict__ src = &obuf[osi * 260 + c16 * 16];
#pragma unroll
        for (int i = 0; i < 4; ++i)        // 64B contiguous per thread
            *(float4*)&out[base + i * 4] = *(const float4*)&src[i * 4];
    }
}

extern "C" void kernel_launch(void* const* d_in, const int* in_sizes, int n_in,
                              void* d_out, int out_size, void* d_ws, size_t ws_size,
                              hipStream_t stream) {
    const float* x  = (const float*)d_in[0];
    const float* W1 = (const float*)d_in[1];
    const float* b1 = (const float*)d_in[2];
    const float* W2 = (const float*)d_in[3];
    const float* b2 = (const float*)d_in[4];
    float* out = (float*)d_out;
    short* lwb = (short*)d_ws;   // 27648 bf16 = 55 KB

    lw_kernel<<<dim3(7, 4), 256, 0, stream>>>(W1, b1, W2, b2, lwb);
    meta_up_mfma<<<4 * HH * 3, 192, 0, stream>>>(x, lwb, out);
}